// Round 16
// baseline (77.813 us; speedup 1.0000x reference)
//
#include <hip/hip_runtime.h>

#define N_PTS   4096
#define N_BATCH 16
#define INV_CNT (1.0f / (2.0f * N_BATCH * N_PTS))
#define AROW_BYTES ((size_t)2 * N_BATCH * N_PTS * 16 * 2)   // 4 MB
#define NBLK    1024               // main-kernel blocks

typedef _Float16 f16x8  __attribute__((ext_vector_type(8)));
#define AS1 __attribute__((address_space(1)))
#define AS3 __attribute__((address_space(3)))

// 32x32x16 f16 MFMA, K-slot packing (split o = oh + ol, p = ph + pl in f16):
//   A-row (opposite point o): [-2oh_x,-2oh_y,-2oh_z, -2ol_x,-2ol_y,-2ol_z,
//                              -2oh_x,-2oh_y | -2oh_z, o2h, o2l, 0...]
//   B-col (query p):          [ph_x,ph_y,ph_z, ph_x,ph_y,ph_z, pl_x,pl_y |
//                              pl_z, 1, 1, 0...]
//   => C = |o|^2 - 2 o.p   (dropped ol.pl ~2^-22; verified R5-R15, absmax 0.0)
__global__ __launch_bounds__(256) void prep_kernel(
    const float* __restrict__ tpl, const float* __restrict__ src,
    _Float16* __restrict__ arow, float* __restrict__ out) {
    int pt = blockIdx.x * 256 + threadIdx.x;          // 0..131071 (T set, then S set)
    if (pt == 0) out[0] = 0.0f;                       // fallback path runs after
    const float* p = (pt < 65536 ? tpl : src) + (size_t)(pt & 65535) * 3;
    float x = p[0], y = p[1], z = p[2];
    float o2 = fmaf(x, x, fmaf(y, y, z * z));
    _Float16 xh = (_Float16)x, yh = (_Float16)y, zh = (_Float16)z;
    _Float16 xl = (_Float16)(x - (float)xh);
    _Float16 yl = (_Float16)(y - (float)yh);
    _Float16 zl = (_Float16)(z - (float)zh);
    _Float16 o2h = (_Float16)o2;
    _Float16 o2l = (_Float16)(o2 - (float)o2h);
    const _Float16 m2 = (_Float16)-2.0f;              // exact power-of-2 scale
    f16x8 v0, v1;
    v0[0] = m2 * xh; v0[1] = m2 * yh; v0[2] = m2 * zh;
    v0[3] = m2 * xl; v0[4] = m2 * yl; v0[5] = m2 * zl;
    v0[6] = m2 * xh; v0[7] = m2 * yh;
    v1[0] = m2 * zh; v1[1] = o2h; v1[2] = o2l;
    v1[3] = (_Float16)0.0f; v1[4] = (_Float16)0.0f; v1[5] = (_Float16)0.0f;
    v1[6] = (_Float16)0.0f; v1[7] = (_Float16)0.0f;
    *(f16x8*)(arow + (size_t)pt * 16)     = v0;
    *(f16x8*)(arow + (size_t)pt * 16 + 8) = v1;
}

// ---- asm blocks (chunk-local state). Banks: A = v[32:47]+v[64:79];
//      B = v[48:63]+v[80:95]; zero-C = v[96:111] re-zeroed per chunk. ----
#define FD(a,x,y) "v_min3_f32 %[" #a "], v" #x ", v" #y ", %[" #a "]\n\t"
#define FOLD_A FD(acc0,32,33) FD(acc1,34,35) FD(acc0,36,37) FD(acc1,38,39) \
               FD(acc0,40,41) FD(acc1,42,43) FD(acc0,44,45) FD(acc1,46,47) \
               FD(acc2,64,65) FD(acc3,66,67) FD(acc2,68,69) FD(acc3,70,71) \
               FD(acc2,72,73) FD(acc3,74,75) FD(acc2,76,77) FD(acc3,78,79)
#define FOLD_B FD(acc0,48,49) FD(acc1,50,51) FD(acc0,52,53) FD(acc1,54,55) \
               FD(acc0,56,57) FD(acc1,58,59) FD(acc0,60,61) FD(acc1,62,63) \
               FD(acc2,80,81) FD(acc3,82,83) FD(acc2,84,85) FD(acc3,86,87) \
               FD(acc2,88,89) FD(acc3,90,91) FD(acc2,92,93) FD(acc3,94,95)
#define MF_A(d) \
  "v_mfma_f32_32x32x16_f16 v[32:47], %[" #d "], %[bf0], v[96:111]\n\t" \
  "v_mfma_f32_32x32x16_f16 v[64:79], %[" #d "], %[bf1], v[96:111]\n\t"
#define MF_B(d) \
  "v_mfma_f32_32x32x16_f16 v[48:63], %[" #d "], %[bf0], v[96:111]\n\t" \
  "v_mfma_f32_32x32x16_f16 v[80:95], %[" #d "], %[bf1], v[96:111]\n\t"
#define DSR(d,off) "ds_read_b128 %[" #d "], %[dsa] offset:" #off "\n\t"
#define WL(n) "s_waitcnt lgkmcnt(" #n ")\n\t"
#define ZM(r) "v_mov_b32 v" #r ", 0\n\t"
#define NOP3 "s_nop 7\n\t" "s_nop 7\n\t" "s_nop 7\n\t"

// R16: NB=2 AND 4 waves/SIMD. Grid (32,16,2) = 1024 blocks x 4 waves
// (qg x kh), 4 blocks/CU = 16 waves/CU. Each wave: 64 tiles (its K-half) in
// 8-tile chunks via double-buffered LDS (2 halves x 2 bufs x 8 KB = 32 KB).
// R11 vs R12-R15 isolated the binder as latency at 2 waves/SIMD (~25% issue
// util across ALL memory variants) -- this doubles the hole-filling waves.
__global__ __launch_bounds__(256, 4) void chamfer_mfma(
    const float* __restrict__ tpl, const float* __restrict__ src,
    const _Float16* __restrict__ arow, float* __restrict__ blocksum,
    float* __restrict__ out) {
    __shared__ uint4 sbuf[2][2][512];   // [K-half][dbuf][8 KB]
    __shared__ float cmb[2][2][2][32];  // [qg][kh][frag][col]
    __shared__ float wsum[4];

    const int tid = threadIdx.x;
    const int wv = tid >> 6, lane = tid & 63;
    const int n = lane & 31, g = lane >> 5;           // B col / K-half-of-frag
    const int qg = wv & 1, kh = wv >> 1;              // query-group / K-half
    // --- XCD-locality remap (bijection on [0,1024)) ---
    const int lin = blockIdx.x + 32 * (blockIdx.y + 16 * blockIdx.z);
    const int s_  = lin >> 3;                         // 0..127
    const int qb  = s_ & 31;
    const int region = (lin & 7) + 8 * (s_ >> 5);     // 0..31 -> one XCD
    const int batch  = region & 15;
    const int dir    = region >> 4;

    const float* qpts = (dir == 0) ? src : tpl;       // dist1: query = source
    const _Float16* abase = arow + ((dir == 0) ? (size_t)0 : (size_t)65536 * 16)
                          + (size_t)batch * 4096 * 16;

    // Two B fragments (frag i -> query qb*128 + qg*64 + i*32 + n) + |p|^2.
    f16x8 bfr[2];
    float p2[2];
    #pragma unroll
    for (int i = 0; i < 2; ++i) {
        const int q = qb * 128 + qg * 64 + i * 32 + n;
        const float* p = qpts + (size_t)(batch * 4096 + q) * 3;
        float px = p[0], py = p[1], pz = p[2];
        p2[i] = fmaf(px, px, fmaf(py, py, pz * pz));
        _Float16 xh = (_Float16)px, yh = (_Float16)py, zh = (_Float16)pz;
        _Float16 xl = (_Float16)(px - (float)xh);
        _Float16 yl = (_Float16)(py - (float)yh);
        _Float16 zl = (_Float16)(pz - (float)zh);
        f16x8 b;
        if (g == 0) {
            b[0] = xh; b[1] = yh; b[2] = zh;
            b[3] = xh; b[4] = yh; b[5] = zh;
            b[6] = xl; b[7] = yl;
        } else {
            b[0] = zl; b[1] = (_Float16)1.0f; b[2] = (_Float16)1.0f;
            b[3] = (_Float16)0.0f; b[4] = (_Float16)0.0f; b[5] = (_Float16)0.0f;
            b[6] = (_Float16)0.0f; b[7] = (_Float16)0.0f;
        }
        bfr[i] = b;
    }

    // Staging: per chunk step, block stages 16 KB (8 KB per K-half).
    // Wave wv stages half (wv>>1), segment (wv&1): 4 x 1 KB load_lds,
    // lds dest = wave-uniform base + lane*16 (verified R15).
    const char* gstage = (const char*)abase + (wv >> 1) * 65536
                       + (wv & 1) * 1024 + lane * 16;
    #define STAGE(ch)                                                          \
        {                                                                      \
            const char* gp = gstage + (ch) * 8192;                             \
            AS3 char* lp = (AS3 char*)&sbuf[wv >> 1][(ch) & 1][0]              \
                         + (wv & 1) * 1024;                                    \
            _Pragma("unroll")                                                  \
            for (int j = 0; j < 4; ++j)                                        \
                __builtin_amdgcn_global_load_lds(                              \
                    (const AS1 unsigned*)(gp + j * 2048),                      \
                    (AS3 unsigned*)(lp + j * 2048), 16, 0, 0);                 \
        }

    const int lane_off = n * 32 + g * 16;
    const unsigned dsa0 = (unsigned)(size_t)((AS3 char*)&sbuf[kh][0][0]) + lane_off;
    const unsigned dsa1 = (unsigned)(size_t)((AS3 char*)&sbuf[kh][1][0]) + lane_off;

    float acc0 = 1e30f, acc1 = 1e30f, acc2 = 1e30f, acc3 = 1e30f;
    f16x8 d0, d1, d2, d3;

    STAGE(0)
    #pragma unroll 1
    for (int c = 0; c < 8; ++c) {
        if (c < 7) {
            STAGE(c + 1)
            asm volatile("s_waitcnt vmcnt(4)\n\ts_barrier" ::: "memory");
        } else {
            asm volatile("s_waitcnt vmcnt(0)\n\ts_barrier" ::: "memory");
        }
        const unsigned dsa = (c & 1) ? dsa1 : dsa0;

        asm volatile(
            ZM(96) ZM(97) ZM(98) ZM(99) ZM(100) ZM(101) ZM(102) ZM(103)
            ZM(104) ZM(105) ZM(106) ZM(107) ZM(108) ZM(109) ZM(110) ZM(111)
            DSR(d0,0) DSR(d1,1024) DSR(d2,2048) DSR(d3,3072)
            WL(3) MF_A(d0) DSR(d0,4096) NOP3         // t0
            WL(3) MF_B(d1) DSR(d1,5120) FOLD_A       // t1
            WL(3) MF_A(d2) DSR(d2,6144) FOLD_B       // t2
            WL(3) MF_B(d3) DSR(d3,7168) FOLD_A       // t3
            WL(3) MF_A(d0) FOLD_B                    // t4
            WL(2) MF_B(d1) FOLD_A                    // t5
            WL(1) MF_A(d2) FOLD_B                    // t6
            WL(0) MF_B(d3) FOLD_A                    // t7
            NOP3 FOLD_B                              // tail: t7's D
            : [d0]"=&v"(d0), [d1]"=&v"(d1), [d2]"=&v"(d2), [d3]"=&v"(d3),
              [acc0]"+v"(acc0), [acc1]"+v"(acc1),
              [acc2]"+v"(acc2), [acc3]"+v"(acc3)
            : [bf0]"v"(bfr[0]), [bf1]"v"(bfr[1]), [dsa]"v"(dsa)
            : "memory",
              "v32","v33","v34","v35","v36","v37","v38","v39",
              "v40","v41","v42","v43","v44","v45","v46","v47",
              "v48","v49","v50","v51","v52","v53","v54","v55",
              "v56","v57","v58","v59","v60","v61","v62","v63",
              "v64","v65","v66","v67","v68","v69","v70","v71",
              "v72","v73","v74","v75","v76","v77","v78","v79",
              "v80","v81","v82","v83","v84","v85","v86","v87",
              "v88","v89","v90","v91","v92","v93","v94","v95",
              "v96","v97","v98","v99","v100","v101","v102","v103",
              "v104","v105","v106","v107","v108","v109","v110","v111");

        // this wave's ds_reads all retired (t7 waited lgkmcnt(0)):
        asm volatile("s_barrier" ::: "memory");  // buffer safe to re-stage
    }

    // Per-frag fold across lane halves -> this K-half's per-col min -> LDS.
    float v0 = fminf(acc0, acc1);
    v0 = fminf(v0, __shfl_xor(v0, 32));
    float v1 = fminf(acc2, acc3);
    v1 = fminf(v1, __shfl_xor(v1, 32));
    if (g == 0) {
        cmb[qg][kh][0][n] = v0;
        cmb[qg][kh][1][n] = v1;
    }
    __syncthreads();

    // kh==0 waves combine both K-halves for their query group.
    float s = 0.0f;
    if (kh == 0 && g == 0) {
        float m0 = fminf(cmb[qg][0][0][n], cmb[qg][1][0][n]);
        float m1 = fminf(cmb[qg][0][1][n], cmb[qg][1][1][n]);
        float e0 = fmaxf(m0 + p2[0], 0.0f);            // == min of clamped
        float e1 = fmaxf(m1 + p2[1], 0.0f);
        s = (sqrtf(e0) + sqrtf(e1)) * INV_CNT;
    }
    #pragma unroll
    for (int off = 32; off > 0; off >>= 1) s += __shfl_down(s, off);
    if (lane == 0) wsum[wv] = s;
    __syncthreads();
    if (tid == 0) {
        float t = wsum[0] + wsum[1] + wsum[2] + wsum[3];
        if (blocksum) {
            int flat = (dir * N_BATCH + batch) * 32 + qb;   // remapped coords
            blocksum[flat] = t;                        // unique slot: no atomics
        } else {
            atomicAdd(out, t);                         // fallback (small ws)
        }
    }
}

// Reduce 1024 block sums -> out[0]. Single block, no atomics.
__global__ __launch_bounds__(256) void final_kernel(
    const float* __restrict__ blocksum, float* __restrict__ out) {
    __shared__ float wsum[4];
    float s = 0.0f;
    #pragma unroll
    for (int j = 0; j < NBLK / 256; ++j)
        s += blocksum[j * 256 + threadIdx.x];
    #pragma unroll
    for (int off = 32; off > 0; off >>= 1) s += __shfl_down(s, off);
    if ((threadIdx.x & 63) == 0) wsum[threadIdx.x >> 6] = s;
    __syncthreads();
    if (threadIdx.x == 0) out[0] = wsum[0] + wsum[1] + wsum[2] + wsum[3];
}

extern "C" void kernel_launch(void* const* d_in, const int* in_sizes, int n_in,
                              void* d_out, int out_size, void* d_ws, size_t ws_size,
                              hipStream_t stream) {
    const float* tpl = (const float*)d_in[0];
    const float* src = (const float*)d_in[1];
    float* out = (float*)d_out;
    _Float16* arow = (_Float16*)d_ws;                  // 4 MB
    const bool roomy = ws_size >= AROW_BYTES + NBLK * sizeof(float);
    float* blocksum = roomy ? (float*)((char*)d_ws + AROW_BYTES) : nullptr;

    hipLaunchKernelGGL(prep_kernel, dim3((2 * N_BATCH * N_PTS) / 256),
                       dim3(256), 0, stream, tpl, src, arow, out);
    dim3 grid(32, N_BATCH, 2);                         // 1024 blocks x 4 waves
    hipLaunchKernelGGL(chamfer_mfma, grid, dim3(256), 0, stream,
                       tpl, src, arow, blocksum, out);
    if (roomy)
        hipLaunchKernelGGL(final_kernel, dim3(1), dim3(256), 0, stream,
                           blocksum, out);
}